// Round 7
// baseline (1175.712 us; speedup 1.0000x reference)
//
#include <hip/hip_runtime.h>
#include <hip/hip_bf16.h>
#include <hip/hip_cooperative_groups.h>

namespace cg = cooperative_groups;

// GraphSAGE 3-layer forward, MI355X. Round 7:
//  ONE cooperative mega-kernel (was 9 dispatches; accounting showed ~15us/dispatch
//  overhead dominating ~115us of actual kernel work). Phases separated by
//  grid.sync() + __threadfence() (cross-XCD visibility, G16):
//   P0 zero gcnt | P1 distribute+casts | P2 gemm0+build | P3 agg0
//   P4 gemm1 | P5 agg1 | P6 gemm2 | P7 final+log_softmax
//  Phase bodies identical math to R6 (absmax must stay 0.03125).

typedef __attribute__((ext_vector_type(8))) short bf16x8;
typedef __attribute__((ext_vector_type(4))) float f32x4;

#define NPB 128            // nodes per bucket (bucket = dst >> 7)
#define BCAP 2560          // per-bucket staging capacity
#define EPB 4096           // edges per distribute chunk (16KB LDS stage)
#define EPT 16             // edges per thread (256 thr)
#define CPAD 16            // global counter stride in ints (64B line each)

struct Params {
    const int* dst; const int* srcv;
    const float* x;
    const float* w0; const float* w1; const float* w2;
    const float* w3; const float* w4; const float* w5;
    const float* bl0; const float* bl1; const float* bl2;
    int* gcnt; unsigned int* staging;
    int* row_ptr; int* adj;
    unsigned short* xbf; unsigned short* wbf;
    unsigned short* C; unsigned short* hA; unsigned short* hB;
    float* out;
    int N, E, NB, distChunks, xcastChunks, gemmRows, aggChunks;
};

__device__ __forceinline__ unsigned short f2bf(float f) {
    unsigned int u = __builtin_bit_cast(unsigned int, f);
    u += 0x7fffu + ((u >> 16) & 1u);           // round-to-nearest-even
    return (unsigned short)(u >> 16);
}
__device__ __forceinline__ float bf2f(unsigned int bits16) {
    return __builtin_bit_cast(float, bits16 << 16);
}

// ---------------- GEMM chunk: 128-row x 64-col tile, 4 waves ----------------

__device__ __forceinline__ void gemm_chunk(const unsigned short* __restrict__ H,
                                           const unsigned short* __restrict__ Wl,
                                           const unsigned short* __restrict__ Wr,
                                           unsigned short* __restrict__ Cout,
                                           int bx, int y, int slabs, int ldC, int N) {
    int wave = threadIdx.x >> 6;
    int lane = threadIdx.x & 63;
    int l15 = lane & 15, quad = lane >> 4;
    int half = slabs >> 1;
    const unsigned short* W = (y < half) ? Wl : Wr;
    int wrow0 = (y < half ? y : y - half) * 64;
    int col0 = y * 64;
    int m0 = bx * 128 + wave * 32;

    int r0 = m0 + l15;      if (r0 > N - 1) r0 = N - 1;
    int r1 = m0 + 16 + l15; if (r1 > N - 1) r1 = N - 1;
    const bf16x8* A0 = (const bf16x8*)(H + (size_t)r0 * 128);
    const bf16x8* A1 = (const bf16x8*)(H + (size_t)r1 * 128);

    f32x4 acc[2][4] = {};
#pragma unroll
    for (int ks = 0; ks < 4; ++ks) {
        int vidx = ks * 4 + quad;
        bf16x8 a0 = A0[vidx];
        bf16x8 a1 = A1[vidx];
#pragma unroll
        for (int j = 0; j < 4; ++j) {
            const bf16x8* B = (const bf16x8*)(W + (size_t)(wrow0 + j * 16 + l15) * 128);
            bf16x8 b = B[vidx];
            acc[0][j] = __builtin_amdgcn_mfma_f32_16x16x32_bf16(a0, b, acc[0][j], 0, 0, 0);
            acc[1][j] = __builtin_amdgcn_mfma_f32_16x16x32_bf16(a1, b, acc[1][j], 0, 0, 0);
        }
    }

#pragma unroll
    for (int i = 0; i < 2; ++i)
#pragma unroll
        for (int j = 0; j < 4; ++j)
#pragma unroll
            for (int r = 0; r < 4; ++r) {
                int row = m0 + i * 16 + quad * 4 + r;
                if (row < N) {
                    int col = col0 + j * 16 + l15;
                    Cout[(size_t)row * ldC + col] = f2bf(acc[i][j][r]);
                }
            }
}

// ---------------- Aggregation chunk (wave per node, 16 gathers in flight) ----------------

__device__ __forceinline__ void agg_node(const unsigned short* __restrict__ C,
                                         const int* __restrict__ row_ptr,
                                         const int* __restrict__ adj,
                                         const float* __restrict__ bias,
                                         unsigned short* __restrict__ hout, int node) {
    int lane = threadIdx.x & 63;
    int beg = row_ptr[node], end = row_ptr[node + 1];
    float sx[4] = {}, sy[4] = {};

    int e = beg;
    while (e < end) {
        int cnt = end - e; if (cnt > 64) cnt = 64;
        int c1 = cnt - 1;
        int ll = lane > c1 ? c1 : lane;
        int myidx = adj[e + ll];

        for (int i = 0; i < cnt; i += 16) {
            int rem = cnt - i;
            unsigned int v[16];
#pragma unroll
            for (int j = 0; j < 16; ++j) {
                int tt = i + j; if (tt > c1) tt = c1;
                int s = __shfl(myidx, tt);
                v[j] = ((const unsigned int*)(C + (size_t)s * 256))[lane];
            }
#pragma unroll
            for (int j = 0; j < 16; ++j) {
                float m = (j < rem) ? 1.f : 0.f;
                sx[j & 3] += m * bf2f(v[j] & 0xffffu);
                sy[j & 3] += m * bf2f(v[j] >> 16);
            }
        }
        e += cnt;
    }

    float fx = (sx[0] + sx[1]) + (sx[2] + sx[3]);
    float fy = (sy[0] + sy[1]) + (sy[2] + sy[3]);
    int deg = end - beg;
    float inv = 1.0f / (float)(deg > 1 ? deg : 1);
    float2 bb = ((const float2*)bias)[lane];
    unsigned int rv = ((const unsigned int*)(C + (size_t)node * 256))[64 + lane];
    float ox = fmaxf(fx * inv + bb.x + bf2f(rv & 0xffffu), 0.f);
    float oy = fmaxf(fy * inv + bb.y + bf2f(rv >> 16), 0.f);
    unsigned int pk = (unsigned int)f2bf(ox) | ((unsigned int)f2bf(oy) << 16);
    ((unsigned int*)(hout + (size_t)node * 128))[lane] = pk;
}

__device__ __forceinline__ void final_node(const unsigned short* __restrict__ C,
                                           const int* __restrict__ row_ptr,
                                           const int* __restrict__ adj,
                                           const float* __restrict__ bias,
                                           float* __restrict__ out, int node) {
    int lane = threadIdx.x & 63;
    int beg = row_ptr[node], end = row_ptr[node + 1];
    float a[4] = {};

    int e = beg;
    while (e < end) {
        int cnt = end - e; if (cnt > 64) cnt = 64;
        int c1 = cnt - 1;
        int ll = lane > c1 ? c1 : lane;
        int myidx = adj[e + ll];

        for (int i = 0; i < cnt; i += 16) {
            int rem = cnt - i;
            float v[16];
#pragma unroll
            for (int j = 0; j < 16; ++j) {
                int tt = i + j; if (tt > c1) tt = c1;
                int s = __shfl(myidx, tt);
                v[j] = bf2f((unsigned int)C[(size_t)s * 128 + lane]);
            }
#pragma unroll
            for (int j = 0; j < 16; ++j) {
                float m = (j < rem) ? 1.f : 0.f;
                a[j & 3] += m * v[j];
            }
        }
        e += cnt;
    }

    float sum = (a[0] + a[1]) + (a[2] + a[3]);
    int deg = end - beg;
    float inv = 1.0f / (float)(deg > 1 ? deg : 1);
    float u = sum * inv + bias[lane] + bf2f((unsigned int)C[(size_t)node * 128 + 64 + lane]);

    float m = u;
#pragma unroll
    for (int off = 32; off > 0; off >>= 1) m = fmaxf(m, __shfl_xor(m, off));
    float ex = __expf(u - m);
    float se = ex;
#pragma unroll
    for (int off = 32; off > 0; off >>= 1) se += __shfl_xor(se, off);
    out[(size_t)node * 64 + lane] = (u - m) - __logf(se);
}

// ---------------- mega kernel ----------------

__global__ __launch_bounds__(256, 4) void mega_kernel(Params p) {
    __shared__ unsigned int sh_stage[EPB];   // 16 KB
    __shared__ int sh_a[400];                // dist hist / build lstart
    __shared__ int sh_b[400];                // dist lstart / build hist(128)
    __shared__ int sh_c[400];                // dist gbase / build scn(128)
    __shared__ int sh_scan[256];

    cg::grid_group grid = cg::this_grid();
    const int t = threadIdx.x;

    // ---- P0: zero gcnt ----
    for (int i = blockIdx.x * 256 + t; i < p.NB * CPAD; i += gridDim.x * 256)
        p.gcnt[i] = 0;
    __threadfence();
    grid.sync();

    // ---- P1: distribute + casts ----
    {
        int total = p.distChunks + p.xcastChunks + 160;
        for (int c = blockIdx.x; c < total; c += gridDim.x) {
            if (c < p.distChunks) {
                int e0 = c * EPB;
                unsigned int w[EPT];
                for (int b = t; b < p.NB + 1; b += 256) sh_a[b] = 0;
                __syncthreads();
#pragma unroll
                for (int i = 0; i < EPT; ++i) {
                    int e = e0 + i * 256 + t;
                    unsigned int word = 0xFFFFFFFFu;          // sentinel -> bucket NB
                    if (e < p.E) word = ((unsigned int)p.dst[e] << 16) | (unsigned int)p.srcv[e];
                    w[i] = word;
                    int b = (int)(word >> 23); if (b > p.NB) b = p.NB;
                    atomicAdd(&sh_a[b], 1);
                }
                __syncthreads();
                int b0 = 2 * t, b1 = 2 * t + 1;
                int h0 = (b0 <= p.NB) ? sh_a[b0] : 0;
                int h1 = (b1 <= p.NB) ? sh_a[b1] : 0;
                int pair = h0 + h1;
                sh_scan[t] = pair;
                __syncthreads();
                for (int off = 1; off < 256; off <<= 1) {
                    int v = (t >= off) ? sh_scan[t - off] : 0;
                    __syncthreads();
                    sh_scan[t] += v;
                    __syncthreads();
                }
                int excl = sh_scan[t] - pair;
                if (b0 <= p.NB) sh_b[b0] = excl;
                if (b1 <= p.NB) sh_b[b1] = excl + h0;
                __syncthreads();
                for (int b = t; b < p.NB; b += 256) {
                    int h = sh_a[b];
                    sh_c[b] = h ? atomicAdd(&p.gcnt[b * CPAD], h) : 0;
                }
                for (int b = t; b < p.NB + 1; b += 256) sh_a[b] = sh_b[b];   // cursors
                __syncthreads();
#pragma unroll
                for (int i = 0; i < EPT; ++i) {
                    unsigned int word = w[i];
                    int b = (int)(word >> 23); if (b > p.NB) b = p.NB;
                    int pos = atomicAdd(&sh_a[b], 1);
                    sh_stage[pos] = word;
                }
                __syncthreads();
                int totalv = sh_b[p.NB];
                for (int i = t; i < totalv; i += 256) {
                    unsigned int word = sh_stage[i];
                    int b = (int)(word >> 23);
                    int g = sh_c[b] + (i - sh_b[b]);
                    p.staging[(size_t)b * BCAP + g] = word;
                }
                __syncthreads();        // protect LDS before next chunk
            } else {
                int bid = c - p.distChunks;
                if (bid < p.xcastChunks) {
                    int i = bid * 256 + t;
                    if (i < p.N * 64) {
                        float2 v = ((const float2*)p.x)[i];
                        unsigned int pk = (unsigned int)f2bf(v.x) | ((unsigned int)f2bf(v.y) << 16);
                        ((unsigned int*)p.xbf)[i] = pk;
                    }
                } else {
                    int w = (bid - p.xcastChunks) * 256 + t;
                    if (w < 40960) {
                        const float* src;
                        int local;
                        if      (w < 8192)  { src = p.w0; local = w; }
                        else if (w < 16384) { src = p.w1; local = w - 8192; }
                        else if (w < 24576) { src = p.w2; local = w - 16384; }
                        else if (w < 32768) { src = p.w3; local = w - 24576; }
                        else if (w < 36864) { src = p.w4; local = w - 32768; }
                        else                { src = p.w5; local = w - 36864; }
                        float2 v = ((const float2*)src)[local];
                        unsigned int pk = (unsigned int)f2bf(v.x) | ((unsigned int)f2bf(v.y) << 16);
                        ((unsigned int*)p.wbf)[w] = pk;
                    }
                }
            }
        }
    }
    __threadfence();
    grid.sync();

    const unsigned short* wl0 = p.wbf;
    const unsigned short* wr0 = p.wbf + 16384;
    const unsigned short* wl1 = p.wbf + 32768;
    const unsigned short* wr1 = p.wbf + 49152;
    const unsigned short* wl2 = p.wbf + 65536;
    const unsigned short* wr2 = p.wbf + 73728;

    // ---- P2: gemm0 + build ----
    {
        int g0 = p.gemmRows * 4;
        int total = g0 + p.NB;
        for (int c = blockIdx.x; c < total; c += gridDim.x) {
            if (c < g0) {
                gemm_chunk(p.xbf, wl0, wr0, p.C, c % p.gemmRows, c / p.gemmRows, 4, 256, p.N);
            } else {
                int b = c - g0;
                // per-chunk redundant scan of bucket counts -> bases
                int b0 = 2 * t, b1 = 2 * t + 1;
                int h0 = (b0 < p.NB) ? p.gcnt[b0 * CPAD] : 0;
                int h1 = (b1 < p.NB) ? p.gcnt[b1 * CPAD] : 0;
                int pair = h0 + h1;
                sh_scan[t] = pair;
                __syncthreads();
                for (int off = 1; off < 256; off <<= 1) {
                    int v = (t >= off) ? sh_scan[t - off] : 0;
                    __syncthreads();
                    sh_scan[t] += v;
                    __syncthreads();
                }
                int excl = sh_scan[t] - pair;
                if (b0 < p.NB) sh_a[b0] = excl;
                if (b1 < p.NB) sh_a[b1] = excl + h0;
                if (b == 0 && t == 255) p.row_ptr[p.N] = sh_scan[255];
                __syncthreads();

                int n0 = b * NPB;
                int nb = p.N - n0; if (nb > NPB) nb = NPB;
                int ec = p.gcnt[b * CPAD];
                int bb = sh_a[b];
                const unsigned int* st = p.staging + (size_t)b * BCAP;

                if (t < NPB) sh_b[t] = 0;
                __syncthreads();
                for (int i = t; i < ec; i += 256)
                    atomicAdd(&sh_b[(st[i] >> 16) & (NPB - 1)], 1);
                __syncthreads();
                int v = (t < NPB) ? sh_b[t] : 0;
                if (t < NPB) sh_c[t] = v;
                __syncthreads();
                for (int off = 1; off < NPB; off <<= 1) {
                    int u = (t >= off && t < NPB) ? sh_c[t - off] : 0;
                    __syncthreads();
                    if (t < NPB) sh_c[t] += u;
                    __syncthreads();
                }
                if (t < NPB) sh_b[t] = sh_c[t] - v;   // cursor base
                if (t < nb) p.row_ptr[n0 + t] = bb + (sh_c[t] - v);
                __syncthreads();
                for (int i = t; i < ec; i += 256) {
                    unsigned int pk = st[i];
                    int pos = atomicAdd(&sh_b[(pk >> 16) & (NPB - 1)], 1);
                    p.adj[bb + pos] = (int)(pk & 0xffffu);
                }
                __syncthreads();
            }
        }
    }
    __threadfence();
    grid.sync();

    // ---- P3: agg0 ----
    for (int c = blockIdx.x; c < p.aggChunks; c += gridDim.x) {
        int node = c * 4 + (t >> 6);
        if (node < p.N) agg_node(p.C, p.row_ptr, p.adj, p.bl0, p.hA, node);
    }
    __threadfence();
    grid.sync();

    // ---- P4: gemm1 ----
    {
        int g1 = p.gemmRows * 4;
        for (int c = blockIdx.x; c < g1; c += gridDim.x)
            gemm_chunk(p.hA, wl1, wr1, p.C, c % p.gemmRows, c / p.gemmRows, 4, 256, p.N);
    }
    __threadfence();
    grid.sync();

    // ---- P5: agg1 ----
    for (int c = blockIdx.x; c < p.aggChunks; c += gridDim.x) {
        int node = c * 4 + (t >> 6);
        if (node < p.N) agg_node(p.C, p.row_ptr, p.adj, p.bl1, p.hB, node);
    }
    __threadfence();
    grid.sync();

    // ---- P6: gemm2 ----
    {
        int g2 = p.gemmRows * 2;
        for (int c = blockIdx.x; c < g2; c += gridDim.x)
            gemm_chunk(p.hB, wl2, wr2, p.C, c % p.gemmRows, c / p.gemmRows, 2, 128, p.N);
    }
    __threadfence();
    grid.sync();

    // ---- P7: final + log_softmax ----
    for (int c = blockIdx.x; c < p.aggChunks; c += gridDim.x) {
        int node = c * 4 + (t >> 6);
        if (node < p.N) final_node(p.C, p.row_ptr, p.adj, p.bl2, p.out, node);
    }
}

// ---------------- Launch ----------------

extern "C" void kernel_launch(void* const* d_in, const int* in_sizes, int n_in,
                              void* d_out, int out_size, void* d_ws, size_t ws_size,
                              hipStream_t stream) {
    const int N  = in_sizes[0] / 128;   // 50000
    const int E  = in_sizes[1] / 2;     // 800000
    const int NB = (N + NPB - 1) / NPB; // 391

    char* ws = (char*)d_ws;
    auto alloc = [&](size_t bytes) {
        char* p = ws;
        ws += (bytes + 255) & ~(size_t)255;
        return p;
    };
    Params p;
    p.row_ptr = (int*)alloc((size_t)(N + 1) * 4);
    p.adj     = (int*)alloc((size_t)E * 4);
    p.gcnt    = (int*)alloc((size_t)NB * CPAD * 4);
    p.staging = (unsigned int*)alloc((size_t)NB * BCAP * 4);
    p.xbf = (unsigned short*)alloc((size_t)N * 128 * 2);
    p.wbf = (unsigned short*)alloc((size_t)81920 * 2);
    p.C   = (unsigned short*)alloc((size_t)N * 256 * 2);
    p.hA  = (unsigned short*)alloc((size_t)N * 128 * 2);
    p.hB  = (unsigned short*)alloc((size_t)N * 128 * 2);

    p.dst  = (const int*)d_in[1];
    p.srcv = (const int*)d_in[1] + E;
    p.x    = (const float*)d_in[0];
    p.w0 = (const float*)d_in[2];   // Wl0
    p.w1 = (const float*)d_in[4];   // Wr0
    p.w2 = (const float*)d_in[5];   // Wl1
    p.w3 = (const float*)d_in[7];   // Wr1
    p.w4 = (const float*)d_in[8];   // Wl2
    p.w5 = (const float*)d_in[10];  // Wr2
    p.bl0 = (const float*)d_in[3];
    p.bl1 = (const float*)d_in[6];
    p.bl2 = (const float*)d_in[9];
    p.out = (float*)d_out;

    p.N = N; p.E = E; p.NB = NB;
    p.distChunks = (E + EPB - 1) / EPB;     // 196
    p.xcastChunks = (N * 64 + 255) / 256;   // 12500
    p.gemmRows = (N + 127) / 128;           // 391
    p.aggChunks = (N + 3) / 4;              // 12500

    int occ = 0;
    hipOccupancyMaxActiveBlocksPerMultiprocessor(&occ, mega_kernel, 256, 0);
    if (occ < 1) occ = 1;
    if (occ > 8) occ = 8;
    int gridBlocks = 256 * occ;             // 256 CUs, all co-resident

    void* args[] = { (void*)&p };
    hipLaunchCooperativeKernel(mega_kernel, dim3(gridBlocks), dim3(256), args, 0, stream);
}

// Round 8
// 278.226 us; speedup vs baseline: 4.2257x; 4.2257x over previous
//
#include <hip/hip_runtime.h>
#include <hip/hip_bf16.h>

// GraphSAGE 3-layer forward, MI355X. Round 8 (revert R7 mega-kernel):
//  - R6 multi-dispatch structure restored (R7: unified kernel capped VGPRs at 64,
//    serialized the gather pipeline + spilled; grid.sync spin crushed the fabric)
//  - build merged with gemm0 (both depend only on dist_cast; disjoint block ranges)
//  - C split into compact CL (gathered half) / CR (self half): gather working set
//    halves -> L2/L3 retention after the harness's 256MB poison flush
//  - 8 dispatches: memset, dist_cast, build||gemm0, agg0, gemm1, agg1, gemm2, final

typedef __attribute__((ext_vector_type(8))) short bf16x8;
typedef __attribute__((ext_vector_type(4))) float f32x4;

#define NPB 128            // nodes per bucket (bucket = dst >> 7)
#define BCAP 2560          // per-bucket staging capacity (mean 2048, sd ~45)
#define EPB 8192           // edges per distribute block
#define EPT 32             // edges per thread (256 thr)
#define CPAD 16            // global counter stride in ints (64B line each)

__device__ __forceinline__ unsigned short f2bf(float f) {
    unsigned int u = __builtin_bit_cast(unsigned int, f);
    u += 0x7fffu + ((u >> 16) & 1u);           // round-to-nearest-even
    return (unsigned short)(u >> 16);
}
__device__ __forceinline__ float bf2f(unsigned int bits16) {
    return __builtin_bit_cast(float, bits16 << 16);
}

// ---------------- fused: CSR phase A (distribute) + bf16 casts ----------------
// staging word: dst << 16 | src (both < 65536). bucket = word >> 23 (= dst>>7).

__global__ __launch_bounds__(256) void dist_cast_kernel(
        const int* __restrict__ dst, const int* __restrict__ srcv,
        int* __restrict__ gcnt, unsigned int* __restrict__ staging, int E, int NBc,
        const float* __restrict__ x,
        const float* p0, const float* p1, const float* p2,
        const float* p3, const float* p4, const float* p5,
        unsigned short* __restrict__ xbf, unsigned short* __restrict__ wbf,
        int xpairs, int distBlocks) {
    __shared__ unsigned int stage[EPB];      // 32KB
    __shared__ int hist[400];
    __shared__ int lstart[400];
    __shared__ int gbase[400];
    __shared__ int scanbuf[256];
    int t = threadIdx.x;

    if (blockIdx.x >= distBlocks) {
        // ---- cast path ----
        int bid = blockIdx.x - distBlocks;
        int xblocks = (xpairs + 255) / 256;
        if (bid < xblocks) {
            int i = bid * 256 + t;
            if (i < xpairs) {
                float2 v = ((const float2*)x)[i];
                unsigned int p = (unsigned int)f2bf(v.x) | ((unsigned int)f2bf(v.y) << 16);
                ((unsigned int*)xbf)[i] = p;
            }
        } else {
            int w = (bid - xblocks) * 256 + t;
            if (w < 40960) {
                const float* src;
                int local;
                if      (w < 8192)  { src = p0; local = w; }
                else if (w < 16384) { src = p1; local = w - 8192; }
                else if (w < 24576) { src = p2; local = w - 16384; }
                else if (w < 32768) { src = p3; local = w - 24576; }
                else if (w < 36864) { src = p4; local = w - 32768; }
                else                { src = p5; local = w - 36864; }
                float2 v = ((const float2*)src)[local];
                unsigned int p = (unsigned int)f2bf(v.x) | ((unsigned int)f2bf(v.y) << 16);
                ((unsigned int*)wbf)[w] = p;
            }
        }
        return;
    }

    // ---- distribute path ----
    int e0 = blockIdx.x * EPB;
    unsigned int w[EPT];

    for (int b = t; b < NBc + 1; b += 256) hist[b] = 0;
    __syncthreads();

#pragma unroll
    for (int i = 0; i < EPT; ++i) {
        int e = e0 + i * 256 + t;            // coalesced
        unsigned int word = 0xFFFFFFFFu;     // sentinel -> bucket NBc
        if (e < E) word = ((unsigned int)dst[e] << 16) | (unsigned int)srcv[e];
        w[i] = word;
        int b = (int)(word >> 23); if (b > NBc) b = NBc;
        atomicAdd(&hist[b], 1);
    }
    __syncthreads();

    int b0 = 2 * t, b1 = 2 * t + 1;
    int h0 = (b0 <= NBc) ? hist[b0] : 0;
    int h1 = (b1 <= NBc) ? hist[b1] : 0;
    int pair = h0 + h1;
    scanbuf[t] = pair;
    __syncthreads();
    for (int off = 1; off < 256; off <<= 1) {
        int v = (t >= off) ? scanbuf[t - off] : 0;
        __syncthreads();
        scanbuf[t] += v;
        __syncthreads();
    }
    int excl = scanbuf[t] - pair;
    if (b0 <= NBc) lstart[b0] = excl;
    if (b1 <= NBc) lstart[b1] = excl + h0;
    __syncthreads();

    for (int b = t; b < NBc; b += 256) {
        int h = hist[b];
        gbase[b] = h ? atomicAdd(&gcnt[b * CPAD], h) : 0;
    }
    for (int b = t; b < NBc + 1; b += 256) hist[b] = lstart[b];   // -> LDS cursors
    __syncthreads();

#pragma unroll
    for (int i = 0; i < EPT; ++i) {
        unsigned int word = w[i];
        int b = (int)(word >> 23); if (b > NBc) b = NBc;
        int p = atomicAdd(&hist[b], 1);
        stage[p] = word;
    }
    __syncthreads();

    int total = lstart[NBc];
    for (int i = t; i < total; i += 256) {
        unsigned int word = stage[i];
        int b = (int)(word >> 23);
        int gpos = gbase[b] + (i - lstart[b]);
        staging[(size_t)b * BCAP + gpos] = word;
    }
}

// ---------------- GEMM tile helper: CL/CR split outputs ----------------
// H: N x 128 bf16. Wl/Wr: Dout x 128 bf16. CL/CR: N x Dout bf16 (compact).
// slab y in [0, 2*half): y < half -> Wl/CL slab y, else Wr/CR slab (y-half).

__device__ __forceinline__ void gemm_tile(const unsigned short* __restrict__ H,
                                          const unsigned short* __restrict__ Wl,
                                          const unsigned short* __restrict__ Wr,
                                          unsigned short* __restrict__ CL,
                                          unsigned short* __restrict__ CR,
                                          int bx, int y, int half, int ldC, int N) {
    int wave = threadIdx.x >> 6;
    int lane = threadIdx.x & 63;
    int l15 = lane & 15, quad = lane >> 4;
    const unsigned short* W = (y < half) ? Wl : Wr;
    unsigned short* Cout = (y < half) ? CL : CR;
    int slab = (y < half) ? y : y - half;
    int wrow0 = slab * 64;
    int col0 = slab * 64;
    int m0 = bx * 128 + wave * 32;

    int r0 = m0 + l15;      if (r0 > N - 1) r0 = N - 1;
    int r1 = m0 + 16 + l15; if (r1 > N - 1) r1 = N - 1;
    const bf16x8* A0 = (const bf16x8*)(H + (size_t)r0 * 128);
    const bf16x8* A1 = (const bf16x8*)(H + (size_t)r1 * 128);

    f32x4 acc[2][4] = {};
#pragma unroll
    for (int ks = 0; ks < 4; ++ks) {
        int vidx = ks * 4 + quad;
        bf16x8 a0 = A0[vidx];
        bf16x8 a1 = A1[vidx];
#pragma unroll
        for (int j = 0; j < 4; ++j) {
            const bf16x8* B = (const bf16x8*)(W + (size_t)(wrow0 + j * 16 + l15) * 128);
            bf16x8 b = B[vidx];
            acc[0][j] = __builtin_amdgcn_mfma_f32_16x16x32_bf16(a0, b, acc[0][j], 0, 0, 0);
            acc[1][j] = __builtin_amdgcn_mfma_f32_16x16x32_bf16(a1, b, acc[1][j], 0, 0, 0);
        }
    }

#pragma unroll
    for (int i = 0; i < 2; ++i)
#pragma unroll
        for (int j = 0; j < 4; ++j)
#pragma unroll
            for (int r = 0; r < 4; ++r) {
                int row = m0 + i * 16 + quad * 4 + r;
                if (row < N) {
                    int col = col0 + j * 16 + l15;
                    Cout[(size_t)row * ldC + col] = f2bf(acc[i][j][r]);
                }
            }
}

__global__ __launch_bounds__(256) void gemm_kernel(const unsigned short* __restrict__ H,
                                                   const unsigned short* __restrict__ Wl,
                                                   const unsigned short* __restrict__ Wr,
                                                   unsigned short* __restrict__ CL,
                                                   unsigned short* __restrict__ CR,
                                                   int half, int ldC, int N) {
    gemm_tile(H, Wl, Wr, CL, CR, blockIdx.x, blockIdx.y, half, ldC, N);
}

// ---------------- merged: CSR phase B (build) || gemm0 ----------------

__global__ __launch_bounds__(256) void build_gemm0_kernel(
        const unsigned int* __restrict__ staging, const int* __restrict__ gcnt,
        int* __restrict__ row_ptr, int* __restrict__ adj, int N, int NBc,
        const unsigned short* __restrict__ xbf,
        const unsigned short* __restrict__ wl0, const unsigned short* __restrict__ wr0,
        unsigned short* __restrict__ CL, unsigned short* __restrict__ CR,
        int gemmRows) {
    __shared__ int lstart[400];
    __shared__ int scanbuf[256];
    __shared__ int hist[NPB];
    __shared__ int scn[NPB];
    int t = threadIdx.x;

    if (blockIdx.x >= (unsigned)NBc) {
        int g = blockIdx.x - NBc;
        gemm_tile(xbf, wl0, wr0, CL, CR, g % gemmRows, g / gemmRows, 2, 128, N);
        return;
    }
    int b = blockIdx.x;

    // per-block redundant scan of bucket counts -> base offsets
    int b0 = 2 * t, b1 = 2 * t + 1;
    int h0 = (b0 < NBc) ? gcnt[b0 * CPAD] : 0;
    int h1 = (b1 < NBc) ? gcnt[b1 * CPAD] : 0;
    int pair = h0 + h1;
    scanbuf[t] = pair;
    __syncthreads();
    for (int off = 1; off < 256; off <<= 1) {
        int v = (t >= off) ? scanbuf[t - off] : 0;
        __syncthreads();
        scanbuf[t] += v;
        __syncthreads();
    }
    int excl = scanbuf[t] - pair;
    if (b0 < NBc) lstart[b0] = excl;
    if (b1 < NBc) lstart[b1] = excl + h0;
    if (b == 0 && t == 255) row_ptr[N] = scanbuf[255];   // total == E
    __syncthreads();

    int n0 = b * NPB;
    int nb = N - n0; if (nb > NPB) nb = NPB;
    int ec = gcnt[b * CPAD];
    int bb = lstart[b];
    const unsigned int* st = staging + (size_t)b * BCAP;

    if (t < NPB) hist[t] = 0;
    __syncthreads();
    for (int i = t; i < ec; i += 256)
        atomicAdd(&hist[(st[i] >> 16) & (NPB - 1)], 1);
    __syncthreads();

    int v = (t < NPB) ? hist[t] : 0;
    if (t < NPB) scn[t] = v;
    __syncthreads();
    for (int off = 1; off < NPB; off <<= 1) {
        int u = (t >= off && t < NPB) ? scn[t - off] : 0;
        __syncthreads();
        if (t < NPB) scn[t] += u;
        __syncthreads();
    }
    if (t < NPB) hist[t] = scn[t] - v;      // exclusive prefix -> cursor base
    if (t < nb) row_ptr[n0 + t] = bb + (scn[t] - v);
    __syncthreads();

    for (int i = t; i < ec; i += 256) {
        unsigned int pk = st[i];
        int p = atomicAdd(&hist[(pk >> 16) & (NPB - 1)], 1);
        adj[bb + p] = (int)(pk & 0xffffu);
    }
}

// ---------------- Aggregation (layers 0,1): wave/node, 16 gathers in flight ----------------
// CL: N x 128 bf16 (gathered, compact). CR: N x 128 bf16 (self path).

__global__ __launch_bounds__(256) void agg_relu_kernel(const unsigned short* __restrict__ CL,
                                                       const unsigned short* __restrict__ CR,
                                                       const int* __restrict__ row_ptr,
                                                       const int* __restrict__ adj,
                                                       const float* __restrict__ bias,
                                                       unsigned short* __restrict__ hout, int N) {
    int node = (int)((blockIdx.x * blockDim.x + threadIdx.x) >> 6);
    int lane = threadIdx.x & 63;
    if (node >= N) return;
    int beg = row_ptr[node], end = row_ptr[node + 1];
    float sx[4] = {}, sy[4] = {};

    int e = beg;
    while (e < end) {
        int cnt = end - e; if (cnt > 64) cnt = 64;
        int c1 = cnt - 1;
        int ll = lane > c1 ? c1 : lane;
        int myidx = adj[e + ll];                 // one coalesced load, clamped

        for (int i = 0; i < cnt; i += 16) {
            int rem = cnt - i;
            unsigned int v[16];
#pragma unroll
            for (int j = 0; j < 16; ++j) {
                int tt = i + j; if (tt > c1) tt = c1;
                int s = __shfl(myidx, tt);
                v[j] = ((const unsigned int*)(CL + (size_t)s * 128))[lane];
            }
#pragma unroll
            for (int j = 0; j < 16; ++j) {
                float m = (j < rem) ? 1.f : 0.f;
                sx[j & 3] += m * bf2f(v[j] & 0xffffu);
                sy[j & 3] += m * bf2f(v[j] >> 16);
            }
        }
        e += cnt;
    }

    float fx = (sx[0] + sx[1]) + (sx[2] + sx[3]);
    float fy = (sy[0] + sy[1]) + (sy[2] + sy[3]);
    int deg = end - beg;
    float inv = 1.0f / (float)(deg > 1 ? deg : 1);
    float2 bb = ((const float2*)bias)[lane];
    unsigned int rv = ((const unsigned int*)(CR + (size_t)node * 128))[lane];
    float ox = fmaxf(fx * inv + bb.x + bf2f(rv & 0xffffu), 0.f);
    float oy = fmaxf(fy * inv + bb.y + bf2f(rv >> 16), 0.f);
    unsigned int p = (unsigned int)f2bf(ox) | ((unsigned int)f2bf(oy) << 16);
    ((unsigned int*)(hout + (size_t)node * 128))[lane] = p;
}

// ---------------- Final layer: CL2/CR2 (N x 64), fused log_softmax ----------------

__global__ __launch_bounds__(256) void final_kernel(const unsigned short* __restrict__ CL,
                                                    const unsigned short* __restrict__ CR,
                                                    const int* __restrict__ row_ptr,
                                                    const int* __restrict__ adj,
                                                    const float* __restrict__ bias,
                                                    float* __restrict__ out, int N) {
    int node = (int)((blockIdx.x * blockDim.x + threadIdx.x) >> 6);
    int lane = threadIdx.x & 63;
    if (node >= N) return;
    int beg = row_ptr[node], end = row_ptr[node + 1];
    float a[4] = {};

    int e = beg;
    while (e < end) {
        int cnt = end - e; if (cnt > 64) cnt = 64;
        int c1 = cnt - 1;
        int ll = lane > c1 ? c1 : lane;
        int myidx = adj[e + ll];

        for (int i = 0; i < cnt; i += 16) {
            int rem = cnt - i;
            float v[16];
#pragma unroll
            for (int j = 0; j < 16; ++j) {
                int tt = i + j; if (tt > c1) tt = c1;
                int s = __shfl(myidx, tt);
                v[j] = bf2f((unsigned int)CL[(size_t)s * 64 + lane]);
            }
#pragma unroll
            for (int j = 0; j < 16; ++j) {
                float m = (j < rem) ? 1.f : 0.f;
                a[j & 3] += m * v[j];
            }
        }
        e += cnt;
    }

    float sum = (a[0] + a[1]) + (a[2] + a[3]);
    int deg = end - beg;
    float inv = 1.0f / (float)(deg > 1 ? deg : 1);
    float u = sum * inv + bias[lane] + bf2f((unsigned int)CR[(size_t)node * 64 + lane]);

    float m = u;
#pragma unroll
    for (int off = 32; off > 0; off >>= 1) m = fmaxf(m, __shfl_xor(m, off));
    float ex = __expf(u - m);
    float se = ex;
#pragma unroll
    for (int off = 32; off > 0; off >>= 1) se += __shfl_xor(se, off);
    out[(size_t)node * 64 + lane] = (u - m) - __logf(se);
}

// ---------------- Launch ----------------

extern "C" void kernel_launch(void* const* d_in, const int* in_sizes, int n_in,
                              void* d_out, int out_size, void* d_ws, size_t ws_size,
                              hipStream_t stream) {
    const float* x   = (const float*)d_in[0];
    const int*   ei  = (const int*)d_in[1];
    const float* Wl0 = (const float*)d_in[2];
    const float* bl0 = (const float*)d_in[3];
    const float* Wr0 = (const float*)d_in[4];
    const float* Wl1 = (const float*)d_in[5];
    const float* bl1 = (const float*)d_in[6];
    const float* Wr1 = (const float*)d_in[7];
    const float* Wl2 = (const float*)d_in[8];
    const float* bl2 = (const float*)d_in[9];
    const float* Wr2 = (const float*)d_in[10];
    float* out = (float*)d_out;

    const int N  = in_sizes[0] / 128;   // 50000
    const int E  = in_sizes[1] / 2;     // 800000
    const int NB = (N + NPB - 1) / NPB; // 391

    char* ws = (char*)d_ws;
    auto alloc = [&](size_t bytes) {
        char* p = ws;
        ws += (bytes + 255) & ~(size_t)255;
        return p;
    };
    int*   row_ptr = (int*)alloc((size_t)(N + 1) * 4);
    int*   adj     = (int*)alloc((size_t)E * 4);
    int*   gcnt    = (int*)alloc((size_t)NB * CPAD * 4);
    unsigned int* staging = (unsigned int*)alloc((size_t)NB * BCAP * 4);
    unsigned short* xbf = (unsigned short*)alloc((size_t)N * 128 * 2);
    unsigned short* wbf = (unsigned short*)alloc((size_t)81920 * 2);
    unsigned short* CLb = (unsigned short*)alloc((size_t)N * 128 * 2);  // gather half
    unsigned short* CRb = (unsigned short*)alloc((size_t)N * 128 * 2);  // self half
    unsigned short* hA  = (unsigned short*)alloc((size_t)N * 128 * 2);
    unsigned short* hB  = (unsigned short*)alloc((size_t)N * 128 * 2);

    const int* dstp = ei;       // edge_index row 0 = dst
    const int* srcp = ei + E;   // edge_index row 1 = src

    hipMemsetAsync(gcnt, 0, (size_t)NB * CPAD * 4, stream);

    // K1: fused distribute + casts
    int distBlocks = (E + EPB - 1) / EPB;            // 98
    int xpairs = N * 64;
    int castBlocks = (xpairs + 255) / 256 + 160;
    dist_cast_kernel<<<distBlocks + castBlocks, 256, 0, stream>>>(
        dstp, srcp, gcnt, staging, E, NB,
        x, Wl0, Wr0, Wl1, Wr1, Wl2, Wr2, xbf, wbf, xpairs, distBlocks);

    unsigned short* wl0 = wbf;
    unsigned short* wr0 = wbf + 16384;
    unsigned short* wl1 = wbf + 32768;
    unsigned short* wr1 = wbf + 49152;
    unsigned short* wl2 = wbf + 65536;
    unsigned short* wr2 = wbf + 73728;

    dim3 blk(256);
    int gemmRows = (N + 127) / 128;     // 391
    int aggBlocks = (N * 64 + 255) / 256;

    // K2: build || gemm0  (both depend only on K1)
    build_gemm0_kernel<<<NB + gemmRows * 4, blk, 0, stream>>>(
        staging, gcnt, row_ptr, adj, N, NB, xbf, wl0, wr0, CLb, CRb, gemmRows);

    // K3: agg0
    agg_relu_kernel<<<aggBlocks, blk, 0, stream>>>(CLb, CRb, row_ptr, adj, bl0, hA, N);
    // K4: gemm1
    gemm_kernel<<<dim3(gemmRows, 4), blk, 0, stream>>>(hA, wl1, wr1, CLb, CRb, 2, 128, N);
    // K5: agg1
    agg_relu_kernel<<<aggBlocks, blk, 0, stream>>>(CLb, CRb, row_ptr, adj, bl1, hB, N);
    // K6: gemm2 (Dout=64, compact rows)
    gemm_kernel<<<dim3(gemmRows, 2), blk, 0, stream>>>(hB, wl2, wr2, CLb, CRb, 1, 64, N);
    // K7: final + log_softmax
    final_kernel<<<aggBlocks, blk, 0, stream>>>(CLb, CRb, row_ptr, adj, bl2, out, N);
}